// Round 1
// baseline (23.850 us; speedup 1.0000x reference)
//
#include <hip/hip_runtime.h>
#include <math.h>

// Problem constants (fixed by setup_inputs): B=8, E=8, F=16, T=2048, k=32
constexpr int Bd = 8;
constexpr int Ed = 8;
constexpr int Fd = 16;
constexpr int Td = 2048;
constexpr int K  = 32;

constexpr int TG   = 16;          // t-groups per block (lanes per f)
constexpr int TPT  = 4;           // t's per thread
constexpr int TT   = TG * TPT;    // 64 t covered per block
constexpr int HALO = K - 1;       // 31
constexpr int WIN  = TT + HALO;   // 95 staged |exo| values per f
constexpr int STRIDE = 100;       // LDS row stride (mult of 4 for float4 alignment)

// out[b][e][f][t] for f<16 = sign(q) * sum_j softmax_j(|q|*a_j) * a_j,  a_j = |exo| window
// out[b][e][16][t] = endo[b][e][t]
__global__ __launch_bounds__(256) void tca_kernel(
    const float* __restrict__ endo,
    const float* __restrict__ exo,
    const float* __restrict__ w_expand,
    const float* __restrict__ b_expand,
    float* __restrict__ out)
{
    __shared__ float a_s[Fd * STRIDE];

    const int tid = threadIdx.x;
    const int b   = blockIdx.z;
    const int e   = blockIdx.y;
    const int t0  = blockIdx.x * TT;

    // ---- stage |exo[b, :, t0-31 .. t0+63]| into LDS (zeros for t<0) ----
    for (int l = tid; l < Fd * WIN; l += 256) {
        const int f = l / WIN;
        const int i = l - f * WIN;
        const int t = t0 - HALO + i;
        float v = (t >= 0) ? exo[(b * Fd + f) * Td + t] : 0.f;
        a_s[f * STRIDE + i] = fabsf(v);
    }
    __syncthreads();

    const int f  = tid >> 4;   // 0..15
    const int tg = tid & 15;   // 0..15
    const int t  = t0 + tg * TPT;

    // endo values for this thread's 4 t's (aligned float4)
    const float4 qv = *reinterpret_cast<const float4*>(&endo[(b * Ed + e) * Td + t]);
    float qa[4] = {qv.x, qv.y, qv.z, qv.w};

    // passthrough channel (f == 16 slot) written once per t
    if (f == 0) {
        *reinterpret_cast<float4*>(
            &out[(((b * Ed + e) * (Fd + 1)) + Fd) * Td + t]) = qv;
    }

    // ---- load union window of 35 |exo| values (9 aligned float4 reads) ----
    float va[36];
    const float* base = &a_s[f * STRIDE + tg * TPT];
    #pragma unroll
    for (int k4 = 0; k4 < 9; ++k4) {
        float4 v4 = reinterpret_cast<const float4*>(base)[k4];
        va[k4 * 4 + 0] = v4.x;
        va[k4 * 4 + 1] = v4.y;
        va[k4 * 4 + 2] = v4.z;
        va[k4 * 4 + 3] = v4.w;
    }

    // ---- exact per-window maxes via shared core [3..31] ----
    float core = 0.f;  // values are abs() >= 0
    #pragma unroll
    for (int j = 3; j < 32; ++j) core = fmaxf(core, va[j]);
    float m[4];
    m[0] = fmaxf(fmaxf(va[0],  va[1]),  fmaxf(va[2],  core));
    m[1] = fmaxf(fmaxf(va[1],  va[2]),  fmaxf(va[32], core));
    m[2] = fmaxf(fmaxf(va[2],  va[32]), fmaxf(va[33], core));
    m[3] = fmaxf(fmaxf(va[32], va[33]), fmaxf(va[34], core));

    const float wf = w_expand[e * Fd + f];
    const float bf = b_expand[e * Fd + f];

    float res[4];
    #pragma unroll
    for (int p = 0; p < TPT; ++p) {
        const float q  = fmaf(qa[p], wf, bf);
        const float aq = fabsf(q);
        const float mp = m[p];
        float num = 0.f, den = 0.f;
        #pragma unroll
        for (int j = 0; j < K; ++j) {
            const float a  = va[p + j];
            const float x  = aq * (a - mp);   // <= 0, no overflow; max term -> exp(0)=1 so den >= 1
            const float ex = __expf(x);
            den += ex;
            num  = fmaf(ex, a, num);
        }
        const float s = (q > 0.f) ? 1.f : ((q < 0.f) ? -1.f : 0.f);
        res[p] = s * num / den;
    }

    float4 r = make_float4(res[0], res[1], res[2], res[3]);
    *reinterpret_cast<float4*>(
        &out[(((b * Ed + e) * (Fd + 1)) + f) * Td + t]) = r;
}

extern "C" void kernel_launch(void* const* d_in, const int* in_sizes, int n_in,
                              void* d_out, int out_size, void* d_ws, size_t ws_size,
                              hipStream_t stream) {
    const float* endo = (const float*)d_in[0];
    const float* exo  = (const float*)d_in[1];
    const float* w    = (const float*)d_in[2];
    const float* bb   = (const float*)d_in[3];
    float* out = (float*)d_out;

    dim3 grid(Td / TT, Ed, Bd);   // (32, 8, 8) = 2048 blocks
    tca_kernel<<<grid, 256, 0, stream>>>(endo, exo, w, bb, out);
}

// Round 2
// 21.415 us; speedup vs baseline: 1.1137x; 1.1137x over previous
//
#include <hip/hip_runtime.h>
#include <math.h>

// Problem constants (fixed by setup_inputs): B=8, E=8, F=16, T=2048, k=32
constexpr int Bd = 8;
constexpr int Ed = 8;
constexpr int Fd = 16;
constexpr int Td = 2048;
constexpr int K  = 32;

constexpr int TG   = 16;          // t-groups per block (lanes per f)
constexpr int TPT  = 4;           // t's per thread
constexpr int TT   = TG * TPT;    // 64 t covered per block
constexpr int HALO = K - 1;       // 31
constexpr int WIN  = TT + HALO;   // 95 staged |exo| values per f
constexpr int STRIDE = 100;       // LDS row stride (mult of 4 for float4 alignment)

// Algebraic simplification of the reference:
//   product = q*kv; |product| = |q|*|kv|; sign(product)*kv = sign(q)*|kv|
//   out[b][e][f][t] = sign(q) * sum_j softmax_j(|q|*a_j) * a_j,  a_j = |exo| window
//   out[b][e][16][t] = endo[b][e][t]
__global__ __launch_bounds__(256) void tca_kernel(
    const float* __restrict__ endo,
    const float* __restrict__ exo,
    const float* __restrict__ w_expand,
    const float* __restrict__ b_expand,
    float* __restrict__ out)
{
    __shared__ float a_s[Fd * STRIDE];

    const int tid = threadIdx.x;
    const int b   = blockIdx.z;
    const int e   = blockIdx.y;
    const int t0  = blockIdx.x * TT;

    // ---- stage |exo[b, :, t0-31 .. t0+63]| into LDS (zeros for t<0) ----
    for (int l = tid; l < Fd * WIN; l += 256) {
        const int f = l / WIN;
        const int i = l - f * WIN;
        const int t = t0 - HALO + i;
        float v = (t >= 0) ? exo[(b * Fd + f) * Td + t] : 0.f;
        a_s[f * STRIDE + i] = fabsf(v);
    }
    __syncthreads();

    const int f  = tid >> 4;   // 0..15
    const int tg = tid & 15;   // 0..15
    const int t  = t0 + tg * TPT;

    // endo values for this thread's 4 t's (aligned float4)
    const float4 qv = *reinterpret_cast<const float4*>(&endo[(b * Ed + e) * Td + t]);
    float qa[4] = {qv.x, qv.y, qv.z, qv.w};

    // passthrough channel (f == 16 slot) written once per t
    if (f == 0) {
        *reinterpret_cast<float4*>(
            &out[(((b * Ed + e) * (Fd + 1)) + Fd) * Td + t]) = qv;
    }

    // ---- load union window of 35 |exo| values (9 aligned float4 reads) ----
    float va[36];
    const float* base = &a_s[f * STRIDE + tg * TPT];
    #pragma unroll
    for (int k4 = 0; k4 < 9; ++k4) {
        float4 v4 = reinterpret_cast<const float4*>(base)[k4];
        va[k4 * 4 + 0] = v4.x;
        va[k4 * 4 + 1] = v4.y;
        va[k4 * 4 + 2] = v4.z;
        va[k4 * 4 + 3] = v4.w;
    }

    // ---- exact per-window maxes via shared core [3..31], 4-way tree ----
    float c0m = va[3], c1m = va[4], c2m = va[5], c3m = va[6];
    #pragma unroll
    for (int j = 7; j < 31; j += 4) {
        c0m = fmaxf(c0m, va[j]);
        c1m = fmaxf(c1m, va[j + 1]);
        c2m = fmaxf(c2m, va[j + 2]);
        c3m = fmaxf(c3m, va[j + 3]);
    }
    const float core = fmaxf(fmaxf(c0m, c1m), fmaxf(c2m, fmaxf(c3m, va[31])));
    float m[4];
    m[0] = fmaxf(fmaxf(va[0],  va[1]),  fmaxf(va[2],  core));
    m[1] = fmaxf(fmaxf(va[1],  va[2]),  fmaxf(va[32], core));
    m[2] = fmaxf(fmaxf(va[2],  va[32]), fmaxf(va[33], core));
    m[3] = fmaxf(fmaxf(va[32], va[33]), fmaxf(va[34], core));

    const float wf = w_expand[e * Fd + f];
    const float bf = b_expand[e * Fd + f];
    constexpr float LOG2E = 1.44269504088896340736f;

    float res[4];
    #pragma unroll
    for (int p = 0; p < TPT; ++p) {
        const float q  = fmaf(qa[p], wf, bf);
        const float aq = fabsf(q);
        const float c1 = aq * LOG2E;        // exp(aq*(a-m)) == exp2(a*c1 + c0)
        const float c0 = -m[p] * c1;
        float den0 = 0.f, den1 = 0.f, num0 = 0.f, num1 = 0.f;
        #pragma unroll
        for (int j = 0; j < K; j += 2) {
            const float a0 = va[p + j];
            const float a1 = va[p + j + 1];
            const float e0 = __builtin_amdgcn_exp2f(fmaf(a0, c1, c0));
            const float e1 = __builtin_amdgcn_exp2f(fmaf(a1, c1, c0));
            den0 += e0;
            den1 += e1;
            num0 = fmaf(e0, a0, num0);
            num1 = fmaf(e1, a1, num1);
        }
        const float den = den0 + den1;      // >= 1 (max term is exp2(~0) = 1)
        const float num = num0 + num1;
        const float s = (q > 0.f) ? 1.f : ((q < 0.f) ? -1.f : 0.f);
        res[p] = s * num * __builtin_amdgcn_rcpf(den);
    }

    float4 r = make_float4(res[0], res[1], res[2], res[3]);
    *reinterpret_cast<float4*>(
        &out[(((b * Ed + e) * (Fd + 1)) + f) * Td + t]) = r;
}

extern "C" void kernel_launch(void* const* d_in, const int* in_sizes, int n_in,
                              void* d_out, int out_size, void* d_ws, size_t ws_size,
                              hipStream_t stream) {
    const float* endo = (const float*)d_in[0];
    const float* exo  = (const float*)d_in[1];
    const float* w    = (const float*)d_in[2];
    const float* bb   = (const float*)d_in[3];
    float* out = (float*)d_out;

    dim3 grid(Td / TT, Ed, Bd);   // (32, 8, 8) = 2048 blocks
    tca_kernel<<<grid, 256, 0, stream>>>(endo, exo, w, bb, out);
}

// Round 3
// 16.286 us; speedup vs baseline: 1.4644x; 1.3149x over previous
//
#include <hip/hip_runtime.h>
#include <math.h>

// Problem constants (fixed by setup_inputs): B=8, E=8, F=16, T=2048, k=32
constexpr int Bd = 8;
constexpr int Ed = 8;
constexpr int Fd = 16;
constexpr int Td = 2048;
constexpr int K  = 32;

constexpr int TG   = 16;          // t-groups per block (lanes per f)
constexpr int TPT  = 4;           // t's per thread
constexpr int TT   = TG * TPT;    // 64 t covered per block
constexpr int HALO = K - 1;       // 31
constexpr int WIN  = TT + HALO;   // 95 staged |exo| values per f
constexpr int STRIDE = 100;       // LDS row stride (mult of 4 for float4 alignment)

typedef float f32x2 __attribute__((ext_vector_type(2)));
typedef float f32x4 __attribute__((ext_vector_type(4)));

__device__ __forceinline__ f32x2 pk_fma(f32x2 a, f32x2 b, f32x2 c) {
#if __has_builtin(__builtin_elementwise_fma)
    return __builtin_elementwise_fma(a, b, c);
#else
    f32x2 r; r.x = fmaf(a.x, b.x, c.x); r.y = fmaf(a.y, b.y, c.y); return r;
#endif
}
__device__ __forceinline__ f32x2 pk_max(f32x2 a, f32x2 b) {
#if __has_builtin(__builtin_elementwise_max)
    return __builtin_elementwise_max(a, b);
#else
    f32x2 r; r.x = fmaxf(a.x, b.x); r.y = fmaxf(a.y, b.y); return r;
#endif
}

// Packed inner loop over NPAIR aligned float2 pairs starting at vw[START].
// den/num split into two chains each to shorten dependent-add chains.
template<int START, int NPAIR>
__device__ __forceinline__ void accum_pairs(const f32x2* vw, f32x2 c1v, f32x2 c0v,
                                            f32x2& den_a, f32x2& den_b,
                                            f32x2& num_a, f32x2& num_b) {
    #pragma unroll
    for (int k = 0; k < NPAIR; ++k) {
        const f32x2 a = vw[START + k];
        const f32x2 x = pk_fma(a, c1v, c0v);        // <= 0 by max-shift
        f32x2 e;
        e.x = __builtin_amdgcn_exp2f(x.x);
        e.y = __builtin_amdgcn_exp2f(x.y);
        if (k & 1) { den_b += e; num_b = pk_fma(e, a, num_b); }
        else       { den_a += e; num_a = pk_fma(e, a, num_a); }
    }
}

// Algebraic simplification of the reference:
//   product = q*kv; |product| = |q|*|kv|; sign(product)*kv = sign(q)*|kv|
//   out[b][e][f][t] = sign(q) * sum_j softmax_j(|q|*a_j) * a_j,  a_j = |exo| window
//   out[b][e][16][t] = endo[b][e][t]
__global__ __launch_bounds__(256, 4) void tca_kernel(
    const float* __restrict__ endo,
    const float* __restrict__ exo,
    const float* __restrict__ w_expand,
    const float* __restrict__ b_expand,
    float* __restrict__ out)
{
    __shared__ float a_s[Fd * STRIDE];

    const int tid = threadIdx.x;
    const int b   = blockIdx.z;
    const int e   = blockIdx.y;
    const int t0  = blockIdx.x * TT;

    const int f  = tid >> 4;   // 0..15
    const int tg = tid & 15;   // 0..15
    const int t  = t0 + tg * TPT;

    // issue independent loads early (before the barrier)
    const float4 qv = *reinterpret_cast<const float4*>(&endo[(b * Ed + e) * Td + t]);
    const float wf  = w_expand[e * Fd + f];
    const float bf  = b_expand[e * Fd + f];

    // ---- stage |exo[b, :, t0-31 .. t0+63]| into LDS (zeros for t<0) ----
    // row f staged by its own 16 lanes: no integer division, coalesced 64B runs
    {
        const float* src = &exo[(b * Fd + f) * Td + t0 - HALO];
        #pragma unroll
        for (int k = 0; k < 6; ++k) {
            const int i = tg + k * 16;
            if (i < WIN) {
                const int tt = t0 - HALO + i;
                const float v = (tt >= 0) ? src[i] : 0.f;
                a_s[f * STRIDE + i] = fabsf(v);
            }
        }
    }
    __syncthreads();

    // passthrough channel (f == 16 slot)
    if (f == 0) {
        *reinterpret_cast<float4*>(
            &out[(((b * Ed + e) * (Fd + 1)) + Fd) * Td + t]) = qv;
    }

    // ---- load union window of 35 values as 18 aligned float2 pairs ----
    f32x2 vw[18];
    {
        const f32x4* base = reinterpret_cast<const f32x4*>(&a_s[f * STRIDE + tg * TPT]);
        #pragma unroll
        for (int k4 = 0; k4 < 9; ++k4) {
            const f32x4 v4 = base[k4];
            vw[2 * k4 + 0] = f32x2{v4.x, v4.y};
            vw[2 * k4 + 1] = f32x2{v4.z, v4.w};
        }
    }
    const float va0 = vw[0].x, va1 = vw[0].y, va2 = vw[1].x, va3 = vw[1].y;
    const float va32 = vw[16].x, va33 = vw[16].y, va34 = vw[17].x;

    // ---- exact per-window maxes: packed shared core va[4..31] ----
    f32x2 Pv = vw[2];
    #pragma unroll
    for (int k = 3; k < 16; ++k) Pv = pk_max(Pv, vw[k]);
    const float Pm  = fmaxf(Pv.x, Pv.y);
    const float m12 = fmaxf(va1, fmaxf(va2, va3));
    const float m32 = fmaxf(va32, va33);
    float m[4];
    m[0] = fmaxf(fmaxf(va0, m12), Pm);
    m[1] = fmaxf(fmaxf(m12, va32), Pm);
    m[2] = fmaxf(fmaxf(fmaxf(va2, va3), m32), Pm);
    m[3] = fmaxf(fmaxf(fmaxf(va3, m32), va34), Pm);

    constexpr float LOG2E = 1.44269504088896340736f;
    const float qa[4] = {qv.x, qv.y, qv.z, qv.w};
    float res[4];

    #pragma unroll
    for (int p = 0; p < TPT; ++p) {
        const float q  = fmaf(qa[p], wf, bf);
        const float aq = fabsf(q);
        const float c1 = aq * LOG2E;          // exp(aq*(a-m)) == exp2(a*c1 + c0)
        const float c0 = -m[p] * c1;
        const f32x2 c1v = {c1, c1};
        const f32x2 c0v = {c0, c0};

        f32x2 den_a = {0.f, 0.f}, den_b = {0.f, 0.f};
        f32x2 num_a = {0.f, 0.f}, num_b = {0.f, 0.f};
        float den_s = 0.f, num_s = 0.f;       // scalar edge terms (odd p)

        if (p == 0) {
            accum_pairs<0, 16>(vw, c1v, c0v, den_a, den_b, num_a, num_b);
        } else if (p == 1) {
            // window va[1..32]: scalar va1, pairs vw[1..15] (va[2..31]), scalar va32
            accum_pairs<1, 15>(vw, c1v, c0v, den_a, den_b, num_a, num_b);
            const float e0 = __builtin_amdgcn_exp2f(fmaf(va1,  c1, c0));
            const float e1 = __builtin_amdgcn_exp2f(fmaf(va32, c1, c0));
            den_s = e0 + e1;
            num_s = fmaf(e0, va1, e1 * va32);
        } else if (p == 2) {
            accum_pairs<1, 16>(vw, c1v, c0v, den_a, den_b, num_a, num_b);
        } else {
            // window va[3..34]: scalar va3, pairs vw[2..16] (va[4..33]), scalar va34
            accum_pairs<2, 15>(vw, c1v, c0v, den_a, den_b, num_a, num_b);
            const float e0 = __builtin_amdgcn_exp2f(fmaf(va3,  c1, c0));
            const float e1 = __builtin_amdgcn_exp2f(fmaf(va34, c1, c0));
            den_s = e0 + e1;
            num_s = fmaf(e0, va3, e1 * va34);
        }

        const f32x2 denv = den_a + den_b;
        const f32x2 numv = num_a + num_b;
        const float den = denv.x + denv.y + den_s;   // >= 1 (max term -> exp2(~0)=1)
        const float num = numv.x + numv.y + num_s;
        const float s = (q > 0.f) ? 1.f : ((q < 0.f) ? -1.f : 0.f);
        res[p] = s * num * __builtin_amdgcn_rcpf(den);
    }

    const float4 r = make_float4(res[0], res[1], res[2], res[3]);
    *reinterpret_cast<float4*>(
        &out[(((b * Ed + e) * (Fd + 1)) + f) * Td + t]) = r;
}

extern "C" void kernel_launch(void* const* d_in, const int* in_sizes, int n_in,
                              void* d_out, int out_size, void* d_ws, size_t ws_size,
                              hipStream_t stream) {
    const float* endo = (const float*)d_in[0];
    const float* exo  = (const float*)d_in[1];
    const float* w    = (const float*)d_in[2];
    const float* bb   = (const float*)d_in[3];
    float* out = (float*)d_out;

    dim3 grid(Td / TT, Ed, Bd);   // (32, 8, 8) = 2048 blocks
    tca_kernel<<<grid, 256, 0, stream>>>(endo, exo, w, bb, out);
}